// Round 11
// baseline (206.619 us; speedup 1.0000x reference)
//
#include <hip/hip_runtime.h>
#include <math.h>

#define EDIM 1024
#define NH   16
#define HD   64
#define BATCH 2
#define SEQ  2048
#define NROW (BATCH*SEQ)   // 4096
#define YAT_EPS 0.1f

typedef _Float16 f16;
typedef _Float16 f16x8 __attribute__((ext_vector_type(8)));
typedef _Float16 f16x4 __attribute__((ext_vector_type(4)));
typedef __fp16   h16x2 __attribute__((ext_vector_type(2)));   // cvt_pkrtz native type
typedef float    f32x4 __attribute__((ext_vector_type(4)));

static __device__ __forceinline__ int pk2(float a, float b) {
    union { h16x2 h; int i; } u;
    u.h = __builtin_amdgcn_cvt_pkrtz(a, b);
    return u.i;
}

// async global->LDS, 16B per lane (GEMM staging; verified r6)
static __device__ __forceinline__ void gload16(const f16* g, f16* l) {
    __builtin_amdgcn_global_load_lds(
        (const __attribute__((address_space(1))) void*)g,
        (__attribute__((address_space(3))) void*)l,
        16, 0, 0);
}

// ---------------------------------------------------------------------------
// prep kernel (unchanged)
// ---------------------------------------------------------------------------
__global__ __launch_bounds__(256)
void prep_kernel(const float* __restrict__ x, f16* __restrict__ xb,
                 const float* __restrict__ W0, const float* __restrict__ W1,
                 const float* __restrict__ W2, const float* __restrict__ W3,
                 f16* __restrict__ T0, f16* __restrict__ T1,
                 f16* __restrict__ T2, f16* __restrict__ T3)
{
    const int z = blockIdx.z;
    if (z == 4) {
        const int bid = blockIdx.y * 32 + blockIdx.x;
#pragma unroll
        for (int i = 0; i < 4; ++i) {
            const int off = bid * 4096 + i * 1024 + threadIdx.x * 4;
            const float4 v = *(const float4*)(x + off);
            union { int i2[2]; f16x4 h; } o;
            o.i2[0] = pk2(v.x, v.y);
            o.i2[1] = pk2(v.z, v.w);
            *(f16x4*)(xb + off) = o.h;
        }
        return;
    }
    const float* W = (z == 0) ? W0 : (z == 1) ? W1 : (z == 2) ? W2 : W3;
    f16*         Wt = (z == 0) ? T0 : (z == 1) ? T1 : (z == 2) ? T2 : T3;

    __shared__ float T[32][33];
    const int t = threadIdx.x;
    const int r = t >> 3, c4 = (t & 7) * 4;
    const int bi = blockIdx.x * 32, bj = blockIdx.y * 32;
    const float4 v = *(const float4*)(W + (size_t)(bi + r) * 1024 + bj + c4);
    T[r][c4 + 0] = v.x; T[r][c4 + 1] = v.y; T[r][c4 + 2] = v.z; T[r][c4 + 3] = v.w;
    __syncthreads();
    f16x4 o = {(f16)T[c4 + 0][r], (f16)T[c4 + 1][r], (f16)T[c4 + 2][r], (f16)T[c4 + 3][r]};
    *(f16x4*)(Wt + (size_t)(bj + r) * 1024 + bi + c4) = o;
}

// ---------------------------------------------------------------------------
// MFMA GEMM (r6 structure: global_load_lds staging, no swizzle).
// Round 21 change: QKV back to the m97-proven 4-wave shape <128,128,2>
//   (256 thr, wave-tile 64x64, MT=4 -> 8 ds_read : 16 MFMA per wave-iter,
//   ratio 2.0 vs the 8-wave config's 1.33; m103 measured 912 TF @K=4096).
//   Grid 768 = 3 blocks/CU, 12 waves/CU, LDS 32KB, VGPR cap 170 (no spill).
//   outproj: <64,128,2> unchanged.
// epi: 0 = fp32 [M,N]; 1 = l2norm f16 [b,h,s,d]; 2 = f16 [b,h,d,s].
// ---------------------------------------------------------------------------
template<int BM, int BN, int WM>
__global__ __launch_bounds__(WM * 128, 3)
void gemm_f16(const f16* __restrict__ A,
              const f16* __restrict__ B0, const f16* __restrict__ B1, const f16* __restrict__ B2,
              const float* __restrict__ bi0, const float* __restrict__ bi1, const float* __restrict__ bi2,
              void* __restrict__ o0, void* __restrict__ o1, void* __restrict__ o2,
              int e0, int e1, int e2)
{
    constexpr int NT    = WM * 128;
    constexpr int SR    = NT / 4;
    constexpr int ASL   = BM / SR;
    constexpr int BSL   = BN / SR;
    constexpr int ABUF  = BM * 32;
    constexpr int BBUF  = BN * 32;
    constexpr int WROWS = BM / WM;
    constexpr int MT    = WROWS / 16;
    constexpr int HALVES = BN / 128;
    constexpr int SCH    = 2048 / NT;
    __shared__ __align__(16) char lds[2 * (ABUF + BBUF) * 2];
    f16* As = (f16*)lds;
    f16* Bs = (f16*)lds + 2 * ABUF;

    const int z = blockIdx.z;
    const f16*   Bt   = (z == 0) ? B0  : (z == 1) ? B1  : B2;
    const float* bias = (z == 0) ? bi0 : (z == 1) ? bi1 : bi2;
    void*        Cout = (z == 0) ? o0  : (z == 1) ? o1  : o2;
    const int    epi  = (z == 0) ? e0  : (z == 1) ? e1  : e2;

    const int tid  = threadIdx.x;
    const int lane = tid & 63;
    const int w    = tid >> 6;
    const int cl   = lane & 15;
    const int quad = lane >> 4;
    const int wm = w % WM, wn = w / WM;    // WN = 2
    const int bm = blockIdx.x * BM, bn = blockIdx.y * BN;
    const int wmoff = wm * WROWS;

    const int srow = tid >> 2;
    const int sc   = tid & 3;
    const int scg  = (sc ^ (srow & 3)) * 8;     // pre-swizzled SOURCE col group
    const f16* gA = A  + (size_t)(bm + srow) * 1024 + scg;
    const f16* gB = Bt + (size_t)(bn + srow) * 1024 + scg;
    f16* lA[ASL]; f16* lB[BSL];
#pragma unroll
    for (int i = 0; i < ASL; ++i) lA[i] = As + (srow + i * SR) * 32 + sc * 8;
#pragma unroll
    for (int i = 0; i < BSL; ++i) lB[i] = Bs + (srow + i * SR) * 32 + sc * 8;

    f32x4 acc[MT][4];
#pragma unroll
    for (int i = 0; i < MT; ++i)
#pragma unroll
        for (int j = 0; j < 4; ++j) acc[i][j] = (f32x4){0.f, 0.f, 0.f, 0.f};

#pragma unroll
    for (int i = 0; i < ASL; ++i) gload16(gA + (size_t)i * SR * 1024, lA[i]);
#pragma unroll
    for (int i = 0; i < BSL; ++i) gload16(gB + (size_t)i * SR * 1024, lB[i]);
    __syncthreads();

    const int fsw = (quad ^ (cl & 3)) * 8;

    for (int it = 0; it < 32; ++it) {
        const int buf = it & 1, nb = buf ^ 1;
        if (it < 31) {
            const int kn = (it + 1) * 32;
#pragma unroll
            for (int i = 0; i < ASL; ++i)
                gload16(gA + (size_t)i * SR * 1024 + kn, lA[i] + nb * ABUF);
#pragma unroll
            for (int i = 0; i < BSL; ++i)
                gload16(gB + (size_t)i * SR * 1024 + kn, lB[i] + nb * BBUF);
        }
        f16x8 af[MT], bf[4];
#pragma unroll
        for (int mt = 0; mt < MT; ++mt)
            af[mt] = *(const f16x8*)(&As[buf * ABUF + (wmoff + mt * 16 + cl) * 32 + fsw]);
#pragma unroll
        for (int nt = 0; nt < 4; ++nt)
            bf[nt] = *(const f16x8*)(&Bs[buf * BBUF + (wn * 64 + nt * 16 + cl) * 32 + fsw]);
#pragma unroll
        for (int mt = 0; mt < MT; ++mt)
#pragma unroll
            for (int nt = 0; nt < 4; ++nt)
                acc[mt][nt] = __builtin_amdgcn_mfma_f32_16x16x32_f16(af[mt], bf[nt], acc[mt][nt], 0, 0, 0);
        __syncthreads();
    }

    float bcol[4];
#pragma unroll
    for (int nt = 0; nt < 4; ++nt) bcol[nt] = bias[bn + wn * 64 + nt * 16 + cl];
#pragma unroll
    for (int mt = 0; mt < MT; ++mt)
#pragma unroll
        for (int nt = 0; nt < 4; ++nt)
#pragma unroll
            for (int rg = 0; rg < 4; ++rg) acc[mt][nt][rg] += bcol[nt];

    const int b_idx = bm >> 11, sl0 = bm & (SEQ - 1), h0 = bn >> 6;

    if (epi == 0) {
        float* C = (float*)Cout;
#pragma unroll
        for (int mt = 0; mt < MT; ++mt)
#pragma unroll
            for (int rg = 0; rg < 4; ++rg) {
                const int row = bm + wmoff + mt * 16 + quad * 4 + rg;
#pragma unroll
                for (int nt = 0; nt < 4; ++nt)
                    C[(size_t)row * EDIM + bn + wn * 64 + nt * 16 + cl] = acc[mt][nt][rg];
            }
    } else if (epi == 1) {                // l2norm -> f16 [b,h,s,d]
        if constexpr (BM == 128) {
        f16* C = (f16*)Cout;
        f16* S = (f16*)lds;
#pragma unroll
        for (int h = 0; h < HALVES; ++h) {
            __syncthreads();
            if ((wn >> 1) == h) {
#pragma unroll
                for (int mt = 0; mt < MT; ++mt)
#pragma unroll
                    for (int rg = 0; rg < 4; ++rg) {
                        float ss = 0.f;
#pragma unroll
                        for (int nt = 0; nt < 4; ++nt) ss += acc[mt][nt][rg] * acc[mt][nt][rg];
                        ss += __shfl_xor(ss, 1); ss += __shfl_xor(ss, 2);
                        ss += __shfl_xor(ss, 4); ss += __shfl_xor(ss, 8);
                        const float inv = 1.0f / (sqrtf(ss) + 1e-8f);
                        const int row = wmoff + mt * 16 + quad * 4 + rg;
#pragma unroll
                        for (int nt = 0; nt < 4; ++nt) {
                            const int colh = (wn & 1) * 64 + nt * 16 + cl;
                            S[row * 128 + (((colh >> 3) ^ (row & 15)) * 8) + (colh & 7)] =
                                (f16)(acc[mt][nt][rg] * inv);
                        }
                    }
            }
            __syncthreads();
#pragma unroll
            for (int i = 0; i < SCH; ++i) {
                const int c = tid + i * NT;
                const int s = c >> 4, gi = c & 15;
                f16x8 v = *(const f16x8*)(&S[s * 128 + ((gi ^ (s & 15)) * 8)]);
                const int head = h0 + h * 2 + (gi >> 3), d8 = (gi & 7) * 8;
                *(f16x8*)(C + ((size_t)(b_idx * NH + head) * SEQ + sl0 + s) * HD + d8) = v;
            }
        }
        }
    } else {                              // epi==2: f16 transposed [b,h,d,s]
        if constexpr (BM == 128) {
        f16* C = (f16*)Cout;
        f16* S = (f16*)lds;
#pragma unroll
        for (int h = 0; h < HALVES; ++h) {
            __syncthreads();
            if ((wn >> 1) == h) {
#pragma unroll
                for (int mt = 0; mt < MT; ++mt) {
                    const int s0 = wmoff + mt * 16 + quad * 4;
#pragma unroll
                    for (int nt = 0; nt < 4; ++nt) {
                        const int colh = (wn & 1) * 64 + nt * 16 + cl;
                        f16x4 o = {(f16)acc[mt][nt][0], (f16)acc[mt][nt][1],
                                   (f16)acc[mt][nt][2], (f16)acc[mt][nt][3]};
                        *(f16x4*)(&S[colh * 128 + (((s0 >> 3) ^ (colh & 15)) * 8) + (s0 & 7)]) = o;
                    }
                }
            }
            __syncthreads();
#pragma unroll
            for (int i = 0; i < SCH; ++i) {
                const int c = tid + i * NT;
                const int colh = c >> 4, gi = c & 15;
                f16x8 v = *(const f16x8*)(&S[colh * 128 + ((gi ^ (colh & 15)) * 8)]);
                const int head = h0 + h * 2 + (colh >> 6), d = colh & 63;
                *(f16x8*)(C + ((size_t)(b_idx * NH + head) * HD + d) * SEQ + sl0 + gi * 8) = v;
            }
        }
        }
    }
}

// ---------------------------------------------------------------------------
// Yat attention: VERBATIM r0/r6 kernel (58.2-61.5us, passed 8x). Four
// structural variants (64q, KVBLK=128 x2, split-K=2) all left wall time
// invariant at ~59us -> per-CU issue-throughput-saturated; parked.
// ---------------------------------------------------------------------------
__global__ __launch_bounds__(512, 4)
void yat_attn(const f16* __restrict__ Qh, const f16* __restrict__ Kh,
              const f16* __restrict__ Vt, f16* __restrict__ AO)
{
    __shared__ __align__(16) char lds[49152];
    f16* Qs = (f16*)lds;                    // 128 x 64
    f16* KB = (f16*)(lds + 16384);          // 2 bufs x 4096 f16
    f16* VB = (f16*)(lds + 32768);          // 2 bufs x 4096 f16

    const int tid  = threadIdx.x;
    const int lane = tid & 63;
    const int w    = tid >> 6;
    const int cl   = lane & 15;
    const int quad = lane >> 4;
    const int wm = w & 3;                   // q quarter (32 q)
    const int wk = w >> 2;                  // k half (32 k)
    const int q0 = blockIdx.x * 128;
    const int bh = blockIdx.y;

    const f16* Qg = Qh + (size_t)bh * SEQ * HD;
    const f16* Kg = Kh + (size_t)bh * SEQ * HD;
    const f16* Vg = Vt + (size_t)bh * HD * SEQ;

    const int rkv = tid >> 3;               // 0..63
    const int gkv = tid & 7;
    const f16* gK = Kg + (size_t)rkv * HD + gkv * 8;
    const f16* gV = Vg + (size_t)rkv * SEQ + gkv * 8;
    const int lkOff = rkv * 64 + ((gkv ^ (rkv & 7)) * 8);

    f16x8 kr = *(const f16x8*)(gK);
    f16x8 vr = *(const f16x8*)(gV);

#pragma unroll
    for (int i = 0; i < 2; ++i) {
        const int s0 = tid + i * 512;
        const int row = s0 >> 3, g = s0 & 7;
        f16x8 v = *(const f16x8*)(Qg + (size_t)(q0 + row) * HD + g * 8);
        *(f16x8*)(&Qs[row * 64 + ((g ^ (row & 7)) * 8)]) = v;
    }
    __syncthreads();
    f16x8 qf[2][2];
#pragma unroll
    for (int qt = 0; qt < 2; ++qt)
#pragma unroll
        for (int kb = 0; kb < 2; ++kb)
            qf[qt][kb] = *(const f16x8*)(&Qs[(wm * 32 + qt * 16 + cl) * 64 +
                                             ((kb * 4 + quad) ^ (cl & 7)) * 8]);

    f32x4 O[2][4];
    float rs[2] = {0.f, 0.f};
#pragma unroll
    for (int i = 0; i < 2; ++i)
#pragma unroll
        for (int j = 0; j < 4; ++j) O[i][j] = (f32x4){0.f, 0.f, 0.f, 0.f};

    for (int t = 0; t < 32; ++t) {
        const int buf = t & 1;
        *(f16x8*)(&KB[buf * 4096 + lkOff]) = kr;
        *(f16x8*)(&VB[buf * 4096 + lkOff]) = vr;
        if (t < 31) {
            kr = *(const f16x8*)(gK + (size_t)(t + 1) * 64 * HD);
            vr = *(const f16x8*)(gV + (t + 1) * 64);
        }
        __syncthreads();                    // lgkm drain; next loads in flight

        const f16* Ks = KB + buf * 4096;
        const f16* Vs = VB + buf * 4096;

        // ---- S^T (32k x 32q) = K.Q^T, K=32 MFMAs ----
        f32x4 s[2][2];
#pragma unroll
        for (int kt = 0; kt < 2; ++kt)
#pragma unroll
            for (int qt = 0; qt < 2; ++qt) s[kt][qt] = (f32x4){0.f, 0.f, 0.f, 0.f};
#pragma unroll
        for (int kb = 0; kb < 2; ++kb) {
            const int sw = ((kb * 4 + quad) ^ (cl & 7)) * 8;
            f16x8 af0 = *(const f16x8*)(&Ks[(wk * 32 +  0 + cl) * 64 + sw]);
            f16x8 af1 = *(const f16x8*)(&Ks[(wk * 32 + 16 + cl) * 64 + sw]);
#pragma unroll
            for (int qt = 0; qt < 2; ++qt) {
                s[0][qt] = __builtin_amdgcn_mfma_f32_16x16x32_f16(af0, qf[qt][kb], s[0][qt], 0, 0, 0);
                s[1][qt] = __builtin_amdgcn_mfma_f32_16x16x32_f16(af1, qf[qt][kb], s[1][qt], 0, 0, 0);
            }
        }

        // ---- yat scores p = 4.41*rcp(u) + u - 4.2, u = 1.1 - d ----
        // packed pairs ARE the 16x16x16 A-fragments (k = quad*4 + i)
        f16x4 pa16[2][2];
#pragma unroll
        for (int kt = 0; kt < 2; ++kt)
#pragma unroll
            for (int qt = 0; qt < 2; ++qt) {
                float p[4];
#pragma unroll
                for (int rg = 0; rg < 4; ++rg) {
                    const float u = (1.0f + YAT_EPS) - s[kt][qt][rg];
                    p[rg] = fmaf(4.41f, __builtin_amdgcn_rcpf(u), u - 4.2f);
                    rs[qt] += p[rg];
                }
                union { int i2[2]; f16x4 h; } pk_;
                pk_.i2[0] = pk2(p[0], p[1]);
                pk_.i2[1] = pk2(p[2], p[3]);
                pa16[kt][qt] = pk_.h;
            }

        // ---- O += P.V via 16x16x16 MFMAs (k window: wk*32 + kt*16) ----
#pragma unroll
        for (int kt = 0; kt < 2; ++kt)
#pragma unroll
            for (int dn = 0; dn < 4; ++dn) {
                const int row = dn * 16 + cl;
                const int g = wk * 4 + kt * 2 + (quad >> 1);
                f16x4 vb = *(const f16x4*)(&Vs[row * 64 + ((g ^ (row & 7)) * 8) + (quad & 1) * 4]);
#pragma unroll
                for (int qt = 0; qt < 2; ++qt)
                    O[qt][dn] = __builtin_amdgcn_mfma_f32_16x16x16f16(pa16[kt][qt], vb, O[qt][dn], 0, 0, 0);
            }
    }

    // ---- epilogue: cross-wk reduce rs and O, normalize, store ----
    __syncthreads();
    float* rs_s = (float*)lds;
    float* Ox   = (float*)(lds + 1024);

#pragma unroll
    for (int qt = 0; qt < 2; ++qt) {
        float t = rs[qt];
        t += __shfl_xor(t, 16);
        t += __shfl_xor(t, 32);
        if (quad == 0) rs_s[wk * 128 + wm * 32 + qt * 16 + cl] = t;
    }
    if (wk == 1) {
#pragma unroll
        for (int qt = 0; qt < 2; ++qt)
#pragma unroll
            for (int dn = 0; dn < 4; ++dn)
#pragma unroll
                for (int rg = 0; rg < 4; ++rg)
                    Ox[(wm * 32 + qt * 16 + quad * 4 + rg) * 64 + dn * 16 + cl] = O[qt][dn][rg];
    }
    __syncthreads();
    if (wk == 0) {
        const int b = bh >> 4, h = bh & 15;
#pragma unroll
        for (int qt = 0; qt < 2; ++qt)
#pragma unroll
            for (int rg = 0; rg < 4; ++rg) {
                const int ql = wm * 32 + qt * 16 + quad * 4 + rg;
                const float tot = rs_s[ql] + rs_s[128 + ql];
                const float inv = 1.0f / (tot + 1e-6f);
                const size_t rowoff = ((size_t)b * SEQ + q0 + ql) * EDIM + h * 64;
#pragma unroll
                for (int dn = 0; dn < 4; ++dn)
                    AO[rowoff + dn * 16 + cl] =
                        (f16)((O[qt][dn][rg] + Ox[ql * 64 + dn * 16 + cl]) * inv);
            }
    }
}

// ---------------------------------------------------------------------------
extern "C" void kernel_launch(void* const* d_in, const int* in_sizes, int n_in,
                              void* d_out, int out_size, void* d_ws, size_t ws_size,
                              hipStream_t stream)
{
    const float* x  = (const float*)d_in[0];
    const float* Wq = (const float*)d_in[1];
    const float* bq = (const float*)d_in[2];
    const float* Wk = (const float*)d_in[3];
    const float* bk = (const float*)d_in[4];
    const float* Wv = (const float*)d_in[5];
    const float* bv = (const float*)d_in[6];
    const float* Wo = (const float*)d_in[7];
    const float* bo = (const float*)d_in[8];

    char* p = (char*)d_ws;
    f16* xb  = (f16*)p;                 p += (size_t)NROW * EDIM * 2;   // 8 MB
    f16* Wqt = (f16*)p;                 p += (size_t)EDIM * EDIM * 2;   // 2 MB
    f16* Wkt = (f16*)p;                 p += (size_t)EDIM * EDIM * 2;
    f16* Wvt = (f16*)p;                 p += (size_t)EDIM * EDIM * 2;
    f16* Wot = (f16*)p;                 p += (size_t)EDIM * EDIM * 2;
    f16* Qhb = (f16*)p;                 p += (size_t)NROW * EDIM * 2;   // [b,h,s,d]
    f16* Khb = (f16*)p;                 p += (size_t)NROW * EDIM * 2;
    f16* Vtb = (f16*)p;                 p += (size_t)NROW * EDIM * 2;   // [b,h,d,s]
    f16* AOb = (f16*)p;                 p += (size_t)NROW * EDIM * 2;   // [b,s,e]

    // prep: weight transposes (z 0..3) + x cast (z 4) in one launch
    prep_kernel<<<dim3(32, 32, 5), 256, 0, stream>>>(x, xb, Wq, Wk, Wv, Wo,
                                                     Wqt, Wkt, Wvt, Wot);

    // fused Q/K/V projections: m97-shape 4-wave 128x128 tiles -> 768 blocks
    gemm_f16<128, 128, 2><<<dim3(NROW / 128, EDIM / 128, 3), 256, 0, stream>>>(
        xb, Wqt, Wkt, Wvt, bq, bk, bv, Qhb, Khb, Vtb, 1, 1, 2);

    // attention: 128-q tiles, 64-k tiles -> 512 blocks (verified r0 kernel)
    yat_attn<<<dim3(SEQ / 128, BATCH * NH), 512, 0, stream>>>(Qhb, Khb, Vtb, AOb);

    // output projection: 64x128 tiles -> 512 blocks (r6 config)
    gemm_f16<64, 128, 2><<<dim3(NROW / 64, EDIM / 128, 1), 256, 0, stream>>>(
        AOb, Wot, Wot, Wot, bo, bo, bo, d_out, d_out, d_out, 0, 0, 0);
}

// Round 12
// 194.536 us; speedup vs baseline: 1.0621x; 1.0621x over previous
//
#include <hip/hip_runtime.h>
#include <math.h>

#define EDIM 1024
#define NH   16
#define HD   64
#define BATCH 2
#define SEQ  2048
#define NROW (BATCH*SEQ)   // 4096
#define YAT_EPS 0.1f

typedef _Float16 f16;
typedef _Float16 f16x8 __attribute__((ext_vector_type(8)));
typedef _Float16 f16x4 __attribute__((ext_vector_type(4)));
typedef __fp16   h16x2 __attribute__((ext_vector_type(2)));   // cvt_pkrtz native type
typedef float    f32x4 __attribute__((ext_vector_type(4)));

static __device__ __forceinline__ int pk2(float a, float b) {
    union { h16x2 h; int i; } u;
    u.h = __builtin_amdgcn_cvt_pkrtz(a, b);
    return u.i;
}

// async global->LDS, 16B per lane (GEMM staging; verified r6)
static __device__ __forceinline__ void gload16(const f16* g, f16* l) {
    __builtin_amdgcn_global_load_lds(
        (const __attribute__((address_space(1))) void*)g,
        (__attribute__((address_space(3))) void*)l,
        16, 0, 0);
}

// ---------------------------------------------------------------------------
// prep kernel (unchanged)
// ---------------------------------------------------------------------------
__global__ __launch_bounds__(256)
void prep_kernel(const float* __restrict__ x, f16* __restrict__ xb,
                 const float* __restrict__ W0, const float* __restrict__ W1,
                 const float* __restrict__ W2, const float* __restrict__ W3,
                 f16* __restrict__ T0, f16* __restrict__ T1,
                 f16* __restrict__ T2, f16* __restrict__ T3)
{
    const int z = blockIdx.z;
    if (z == 4) {
        const int bid = blockIdx.y * 32 + blockIdx.x;
#pragma unroll
        for (int i = 0; i < 4; ++i) {
            const int off = bid * 4096 + i * 1024 + threadIdx.x * 4;
            const float4 v = *(const float4*)(x + off);
            union { int i2[2]; f16x4 h; } o;
            o.i2[0] = pk2(v.x, v.y);
            o.i2[1] = pk2(v.z, v.w);
            *(f16x4*)(xb + off) = o.h;
        }
        return;
    }
    const float* W = (z == 0) ? W0 : (z == 1) ? W1 : (z == 2) ? W2 : W3;
    f16*         Wt = (z == 0) ? T0 : (z == 1) ? T1 : (z == 2) ? T2 : T3;

    __shared__ float T[32][33];
    const int t = threadIdx.x;
    const int r = t >> 3, c4 = (t & 7) * 4;
    const int bi = blockIdx.x * 32, bj = blockIdx.y * 32;
    const float4 v = *(const float4*)(W + (size_t)(bi + r) * 1024 + bj + c4);
    T[r][c4 + 0] = v.x; T[r][c4 + 1] = v.y; T[r][c4 + 2] = v.z; T[r][c4 + 3] = v.w;
    __syncthreads();
    f16x4 o = {(f16)T[c4 + 0][r], (f16)T[c4 + 1][r], (f16)T[c4 + 2][r], (f16)T[c4 + 3][r]};
    *(f16x4*)(Wt + (size_t)(bj + r) * 1024 + bi + c4) = o;
}

// ---------------------------------------------------------------------------
// MFMA GEMM (r6-verified, reverted from r11's 4-wave experiment which
// regressed: 12 waves/CU lost to the 8-wave config's 24 at short K).
//   QKV:     <128,128,4> -> 512 thr, 8 waves, 768 blocks = 3/CU.
//   outproj: < 64,128,2> -> 256 thr, 4 waves, 512 blocks = 2/CU.
// epi: 0 = fp32 [M,N]; 1 = l2norm f16 [b,h,s,d]; 2 = f16 [b,h,d,s].
// ---------------------------------------------------------------------------
template<int BM, int BN, int WM>
__global__ __launch_bounds__(WM * 128, 3)
void gemm_f16(const f16* __restrict__ A,
              const f16* __restrict__ B0, const f16* __restrict__ B1, const f16* __restrict__ B2,
              const float* __restrict__ bi0, const float* __restrict__ bi1, const float* __restrict__ bi2,
              void* __restrict__ o0, void* __restrict__ o1, void* __restrict__ o2,
              int e0, int e1, int e2)
{
    constexpr int NT    = WM * 128;
    constexpr int SR    = NT / 4;
    constexpr int ASL   = BM / SR;
    constexpr int BSL   = BN / SR;
    constexpr int ABUF  = BM * 32;
    constexpr int BBUF  = BN * 32;
    constexpr int WROWS = BM / WM;
    constexpr int MT    = WROWS / 16;
    constexpr int HALVES = BN / 128;
    constexpr int SCH    = 2048 / NT;
    __shared__ __align__(16) char lds[2 * (ABUF + BBUF) * 2];
    f16* As = (f16*)lds;
    f16* Bs = (f16*)lds + 2 * ABUF;

    const int z = blockIdx.z;
    const f16*   Bt   = (z == 0) ? B0  : (z == 1) ? B1  : B2;
    const float* bias = (z == 0) ? bi0 : (z == 1) ? bi1 : bi2;
    void*        Cout = (z == 0) ? o0  : (z == 1) ? o1  : o2;
    const int    epi  = (z == 0) ? e0  : (z == 1) ? e1  : e2;

    const int tid  = threadIdx.x;
    const int lane = tid & 63;
    const int w    = tid >> 6;
    const int cl   = lane & 15;
    const int quad = lane >> 4;
    const int wm = w % WM, wn = w / WM;    // WN = 2
    const int bm = blockIdx.x * BM, bn = blockIdx.y * BN;
    const int wmoff = wm * WROWS;

    const int srow = tid >> 2;
    const int sc   = tid & 3;
    const int scg  = (sc ^ (srow & 3)) * 8;     // pre-swizzled SOURCE col group
    const f16* gA = A  + (size_t)(bm + srow) * 1024 + scg;
    const f16* gB = Bt + (size_t)(bn + srow) * 1024 + scg;
    f16* lA[ASL]; f16* lB[BSL];
#pragma unroll
    for (int i = 0; i < ASL; ++i) lA[i] = As + (srow + i * SR) * 32 + sc * 8;
#pragma unroll
    for (int i = 0; i < BSL; ++i) lB[i] = Bs + (srow + i * SR) * 32 + sc * 8;

    f32x4 acc[MT][4];
#pragma unroll
    for (int i = 0; i < MT; ++i)
#pragma unroll
        for (int j = 0; j < 4; ++j) acc[i][j] = (f32x4){0.f, 0.f, 0.f, 0.f};

#pragma unroll
    for (int i = 0; i < ASL; ++i) gload16(gA + (size_t)i * SR * 1024, lA[i]);
#pragma unroll
    for (int i = 0; i < BSL; ++i) gload16(gB + (size_t)i * SR * 1024, lB[i]);
    __syncthreads();

    const int fsw = (quad ^ (cl & 3)) * 8;

    for (int it = 0; it < 32; ++it) {
        const int buf = it & 1, nb = buf ^ 1;
        if (it < 31) {
            const int kn = (it + 1) * 32;
#pragma unroll
            for (int i = 0; i < ASL; ++i)
                gload16(gA + (size_t)i * SR * 1024 + kn, lA[i] + nb * ABUF);
#pragma unroll
            for (int i = 0; i < BSL; ++i)
                gload16(gB + (size_t)i * SR * 1024 + kn, lB[i] + nb * BBUF);
        }
        f16x8 af[MT], bf[4];
#pragma unroll
        for (int mt = 0; mt < MT; ++mt)
            af[mt] = *(const f16x8*)(&As[buf * ABUF + (wmoff + mt * 16 + cl) * 32 + fsw]);
#pragma unroll
        for (int nt = 0; nt < 4; ++nt)
            bf[nt] = *(const f16x8*)(&Bs[buf * BBUF + (wn * 64 + nt * 16 + cl) * 32 + fsw]);
#pragma unroll
        for (int mt = 0; mt < MT; ++mt)
#pragma unroll
            for (int nt = 0; nt < 4; ++nt)
                acc[mt][nt] = __builtin_amdgcn_mfma_f32_16x16x32_f16(af[mt], bf[nt], acc[mt][nt], 0, 0, 0);
        __syncthreads();
    }

    float bcol[4];
#pragma unroll
    for (int nt = 0; nt < 4; ++nt) bcol[nt] = bias[bn + wn * 64 + nt * 16 + cl];
#pragma unroll
    for (int mt = 0; mt < MT; ++mt)
#pragma unroll
        for (int nt = 0; nt < 4; ++nt)
#pragma unroll
            for (int rg = 0; rg < 4; ++rg) acc[mt][nt][rg] += bcol[nt];

    const int b_idx = bm >> 11, sl0 = bm & (SEQ - 1), h0 = bn >> 6;

    if (epi == 0) {
        float* C = (float*)Cout;
#pragma unroll
        for (int mt = 0; mt < MT; ++mt)
#pragma unroll
            for (int rg = 0; rg < 4; ++rg) {
                const int row = bm + wmoff + mt * 16 + quad * 4 + rg;
#pragma unroll
                for (int nt = 0; nt < 4; ++nt)
                    C[(size_t)row * EDIM + bn + wn * 64 + nt * 16 + cl] = acc[mt][nt][rg];
            }
    } else if (epi == 1) {                // l2norm -> f16 [b,h,s,d]
        if constexpr (BM == 128) {
        f16* C = (f16*)Cout;
        f16* S = (f16*)lds;
#pragma unroll
        for (int h = 0; h < HALVES; ++h) {
            __syncthreads();
            if ((wn >> 1) == h) {
#pragma unroll
                for (int mt = 0; mt < MT; ++mt)
#pragma unroll
                    for (int rg = 0; rg < 4; ++rg) {
                        float ss = 0.f;
#pragma unroll
                        for (int nt = 0; nt < 4; ++nt) ss += acc[mt][nt][rg] * acc[mt][nt][rg];
                        ss += __shfl_xor(ss, 1); ss += __shfl_xor(ss, 2);
                        ss += __shfl_xor(ss, 4); ss += __shfl_xor(ss, 8);
                        const float inv = 1.0f / (sqrtf(ss) + 1e-8f);
                        const int row = wmoff + mt * 16 + quad * 4 + rg;
#pragma unroll
                        for (int nt = 0; nt < 4; ++nt) {
                            const int colh = (wn & 1) * 64 + nt * 16 + cl;
                            S[row * 128 + (((colh >> 3) ^ (row & 15)) * 8) + (colh & 7)] =
                                (f16)(acc[mt][nt][rg] * inv);
                        }
                    }
            }
            __syncthreads();
#pragma unroll
            for (int i = 0; i < SCH; ++i) {
                const int c = tid + i * NT;
                const int s = c >> 4, gi = c & 15;
                f16x8 v = *(const f16x8*)(&S[s * 128 + ((gi ^ (s & 15)) * 8)]);
                const int head = h0 + h * 2 + (gi >> 3), d8 = (gi & 7) * 8;
                *(f16x8*)(C + ((size_t)(b_idx * NH + head) * SEQ + sl0 + s) * HD + d8) = v;
            }
        }
        }
    } else {                              // epi==2: f16 transposed [b,h,d,s]
        if constexpr (BM == 128) {
        f16* C = (f16*)Cout;
        f16* S = (f16*)lds;
#pragma unroll
        for (int h = 0; h < HALVES; ++h) {
            __syncthreads();
            if ((wn >> 1) == h) {
#pragma unroll
                for (int mt = 0; mt < MT; ++mt) {
                    const int s0 = wmoff + mt * 16 + quad * 4;
#pragma unroll
                    for (int nt = 0; nt < 4; ++nt) {
                        const int colh = (wn & 1) * 64 + nt * 16 + cl;
                        f16x4 o = {(f16)acc[mt][nt][0], (f16)acc[mt][nt][1],
                                   (f16)acc[mt][nt][2], (f16)acc[mt][nt][3]};
                        *(f16x4*)(&S[colh * 128 + (((s0 >> 3) ^ (colh & 15)) * 8) + (s0 & 7)]) = o;
                    }
                }
            }
            __syncthreads();
#pragma unroll
            for (int i = 0; i < SCH; ++i) {
                const int c = tid + i * NT;
                const int colh = c >> 4, gi = c & 15;
                f16x8 v = *(const f16x8*)(&S[colh * 128 + ((gi ^ (colh & 15)) * 8)]);
                const int head = h0 + h * 2 + (colh >> 6), d = colh & 63;
                *(f16x8*)(C + ((size_t)(b_idx * NH + head) * HD + d) * SEQ + sl0 + gi * 8) = v;
            }
        }
        }
    }
}

// ---------------------------------------------------------------------------
// Yat attention, round 22: T15 double-pipeline. Same per-tile math as r0
// (passed 8x), but score+PV of tile t-1 execute during tile t's S-MFMAs —
// the score VALU is register-only (depends on s_prev), so the MFMA and VALU
// pipes overlap in-wave (m114) instead of serializing (35%+48% summed).
// Triple-buffered K/V (3x16KB = 48KB, Qs freed via Q-direct r3 piece):
// buffer b written at t is read by S(t) and PV(t) in the two following
// barrier intervals; next write at t+3 is behind bar(t+2). No inline asm.
// launch_bounds(512,2): VGPR cap 128 (s_prev adds ~16; grid=512 is 2
// blocks/CU regardless, so no residency loss — avoids the r3 spill trap).
// ---------------------------------------------------------------------------
__global__ __launch_bounds__(512, 2)
void yat_attn(const f16* __restrict__ Qh, const f16* __restrict__ Kh,
              const f16* __restrict__ Vt, f16* __restrict__ AO)
{
    __shared__ __align__(16) char lds[49152];
    f16* KB = (f16*)lds;                    // 3 bufs x 4096 f16 (24 KB)
    f16* VB = (f16*)(lds + 24576);          // 3 bufs x 4096 f16 (24 KB)

    const int tid  = threadIdx.x;
    const int lane = tid & 63;
    const int w    = tid >> 6;
    const int cl   = lane & 15;
    const int quad = lane >> 4;
    const int wm = w & 3;                   // q quarter (32 q)
    const int wk = w >> 2;                  // k half (32 k)
    const int q0 = blockIdx.x * 128;
    const int bh = blockIdx.y;

    const f16* Qg = Qh + (size_t)bh * SEQ * HD;
    const f16* Kg = Kh + (size_t)bh * SEQ * HD;
    const f16* Vg = Vt + (size_t)bh * HD * SEQ;

    const int rkv = tid >> 3;               // 0..63
    const int gkv = tid & 7;
    const f16* gK = Kg + (size_t)rkv * HD + gkv * 8;
    const f16* gV = Vg + (size_t)rkv * SEQ + gkv * 8;
    const int lkOff = rkv * 64 + ((gkv ^ (rkv & 7)) * 8);

    f16x8 kr = *(const f16x8*)(gK);
    f16x8 vr = *(const f16x8*)(gV);

    // Q fragments direct from global (r3-verified piece; frees Qs LDS)
    f16x8 qf[2][2];
#pragma unroll
    for (int qt = 0; qt < 2; ++qt)
#pragma unroll
        for (int kb = 0; kb < 2; ++kb)
            qf[qt][kb] = *(const f16x8*)(Qg + (size_t)(q0 + wm * 32 + qt * 16 + cl) * HD +
                                         (kb * 4 + quad) * 8);

    f32x4 O[2][4];
    float rs[2] = {0.f, 0.f};
#pragma unroll
    for (int i = 0; i < 2; ++i)
#pragma unroll
        for (int j = 0; j < 4; ++j) O[i][j] = (f32x4){0.f, 0.f, 0.f, 0.f};

    // ---- prologue: stage tile 0, S-MFMA(0) -> s_prev ----
    *(f16x8*)(&KB[lkOff]) = kr;
    *(f16x8*)(&VB[lkOff]) = vr;
    kr = *(const f16x8*)(gK + (size_t)64 * HD);
    vr = *(const f16x8*)(gV + 64);
    __syncthreads();

    f32x4 sp[2][2];
#pragma unroll
    for (int kt = 0; kt < 2; ++kt)
#pragma unroll
        for (int qt = 0; qt < 2; ++qt) sp[kt][qt] = (f32x4){0.f, 0.f, 0.f, 0.f};
#pragma unroll
    for (int kb = 0; kb < 2; ++kb) {
        const int sw = ((kb * 4 + quad) ^ (cl & 7)) * 8;
        f16x8 af0 = *(const f16x8*)(&KB[(wk * 32 +  0 + cl) * 64 + sw]);
        f16x8 af1 = *(const f16x8*)(&KB[(wk * 32 + 16 + cl) * 64 + sw]);
#pragma unroll
        for (int qt = 0; qt < 2; ++qt) {
            sp[0][qt] = __builtin_amdgcn_mfma_f32_16x16x32_f16(af0, qf[qt][kb], sp[0][qt], 0, 0, 0);
            sp[1][qt] = __builtin_amdgcn_mfma_f32_16x16x32_f16(af1, qf[qt][kb], sp[1][qt], 0, 0, 0);
        }
    }

    for (int t = 1; t < 32; ++t) {
        const int wb = t % 3;               // write buffer
        const int pb = (t - 1) % 3;         // prev buffer (PV source)
        *(f16x8*)(&KB[wb * 4096 + lkOff]) = kr;
        *(f16x8*)(&VB[wb * 4096 + lkOff]) = vr;
        if (t < 31) {
            kr = *(const f16x8*)(gK + (size_t)(t + 1) * 64 * HD);
            vr = *(const f16x8*)(gV + (t + 1) * 64);
        }
        __syncthreads();

        const f16* Ks = KB + wb * 4096;
        const f16* Vs = VB + pb * 4096;

        // ---- S-MFMA(t) -> sc (independent of score/PV below) ----
        f32x4 sc[2][2];
#pragma unroll
        for (int kt = 0; kt < 2; ++kt)
#pragma unroll
            for (int qt = 0; qt < 2; ++qt) sc[kt][qt] = (f32x4){0.f, 0.f, 0.f, 0.f};
#pragma unroll
        for (int kb = 0; kb < 2; ++kb) {
            const int sw = ((kb * 4 + quad) ^ (cl & 7)) * 8;
            f16x8 af0 = *(const f16x8*)(&Ks[(wk * 32 +  0 + cl) * 64 + sw]);
            f16x8 af1 = *(const f16x8*)(&Ks[(wk * 32 + 16 + cl) * 64 + sw]);
#pragma unroll
            for (int qt = 0; qt < 2; ++qt) {
                sc[0][qt] = __builtin_amdgcn_mfma_f32_16x16x32_f16(af0, qf[qt][kb], sc[0][qt], 0, 0, 0);
                sc[1][qt] = __builtin_amdgcn_mfma_f32_16x16x32_f16(af1, qf[qt][kb], sc[1][qt], 0, 0, 0);
            }
        }

        // ---- yat scores for tile t-1 (register-only, overlaps S-MFMAs) ----
        f16x4 pa16[2][2];
#pragma unroll
        for (int kt = 0; kt < 2; ++kt)
#pragma unroll
            for (int qt = 0; qt < 2; ++qt) {
                float p[4];
#pragma unroll
                for (int rg = 0; rg < 4; ++rg) {
                    const float u = (1.0f + YAT_EPS) - sp[kt][qt][rg];
                    p[rg] = fmaf(4.41f, __builtin_amdgcn_rcpf(u), u - 4.2f);
                    rs[qt] += p[rg];
                }
                union { int i2[2]; f16x4 h; } pk_;
                pk_.i2[0] = pk2(p[0], p[1]);
                pk_.i2[1] = pk2(p[2], p[3]);
                pa16[kt][qt] = pk_.h;
            }

        // ---- PV for tile t-1 (Vs = prev buffer, protected by barriers) ----
#pragma unroll
        for (int kt = 0; kt < 2; ++kt)
#pragma unroll
            for (int dn = 0; dn < 4; ++dn) {
                const int row = dn * 16 + cl;
                const int g = wk * 4 + kt * 2 + (quad >> 1);
                f16x4 vb = *(const f16x4*)(&Vs[row * 64 + ((g ^ (row & 7)) * 8) + (quad & 1) * 4]);
#pragma unroll
                for (int qt = 0; qt < 2; ++qt)
                    O[qt][dn] = __builtin_amdgcn_mfma_f32_16x16x16f16(pa16[kt][qt], vb, O[qt][dn], 0, 0, 0);
            }

        // roll the pipeline
#pragma unroll
        for (int kt = 0; kt < 2; ++kt)
#pragma unroll
            for (int qt = 0; qt < 2; ++qt) sp[kt][qt] = sc[kt][qt];
    }

    // ---- tail: score + PV for tile 31 (buf 31%3 = 1) ----
    {
        const f16* Vs = VB + (31 % 3) * 4096;
        f16x4 pa16[2][2];
#pragma unroll
        for (int kt = 0; kt < 2; ++kt)
#pragma unroll
            for (int qt = 0; qt < 2; ++qt) {
                float p[4];
#pragma unroll
                for (int rg = 0; rg < 4; ++rg) {
                    const float u = (1.0f + YAT_EPS) - sp[kt][qt][rg];
                    p[rg] = fmaf(4.41f, __builtin_amdgcn_rcpf(u), u - 4.2f);
                    rs[qt] += p[rg];
                }
                union { int i2[2]; f16x4 h; } pk_;
                pk_.i2[0] = pk2(p[0], p[1]);
                pk_.i2[1] = pk2(p[2], p[3]);
                pa16[kt][qt] = pk_.h;
            }
#pragma unroll
        for (int kt = 0; kt < 2; ++kt)
#pragma unroll
            for (int dn = 0; dn < 4; ++dn) {
                const int row = dn * 16 + cl;
                const int g = wk * 4 + kt * 2 + (quad >> 1);
                f16x4 vb = *(const f16x4*)(&Vs[row * 64 + ((g ^ (row & 7)) * 8) + (quad & 1) * 4]);
#pragma unroll
                for (int qt = 0; qt < 2; ++qt)
                    O[qt][dn] = __builtin_amdgcn_mfma_f32_16x16x16f16(pa16[kt][qt], vb, O[qt][dn], 0, 0, 0);
            }
    }

    // ---- epilogue: cross-wk reduce rs and O, normalize, store (r0) ----
    __syncthreads();                        // all PV reads done before scratch
    float* rs_s = (float*)lds;
    float* Ox   = (float*)(lds + 1024);

#pragma unroll
    for (int qt = 0; qt < 2; ++qt) {
        float t = rs[qt];
        t += __shfl_xor(t, 16);
        t += __shfl_xor(t, 32);
        if (quad == 0) rs_s[wk * 128 + wm * 32 + qt * 16 + cl] = t;
    }
    if (wk == 1) {
#pragma unroll
        for (int qt = 0; qt < 2; ++qt)
#pragma unroll
            for (int dn = 0; dn < 4; ++dn)
#pragma unroll
                for (int rg = 0; rg < 4; ++rg)
                    Ox[(wm * 32 + qt * 16 + quad * 4 + rg) * 64 + dn * 16 + cl] = O[qt][dn][rg];
    }
    __syncthreads();
    if (wk == 0) {
        const int b = bh >> 4, h = bh & 15;
#pragma unroll
        for (int qt = 0; qt < 2; ++qt)
#pragma unroll
            for (int rg = 0; rg < 4; ++rg) {
                const int ql = wm * 32 + qt * 16 + quad * 4 + rg;
                const float tot = rs_s[ql] + rs_s[128 + ql];
                const float inv = 1.0f / (tot + 1e-6f);
                const size_t rowoff = ((size_t)b * SEQ + q0 + ql) * EDIM + h * 64;
#pragma unroll
                for (int dn = 0; dn < 4; ++dn)
                    AO[rowoff + dn * 16 + cl] =
                        (f16)((O[qt][dn][rg] + Ox[ql * 64 + dn * 16 + cl]) * inv);
            }
    }
}

// ---------------------------------------------------------------------------
extern "C" void kernel_launch(void* const* d_in, const int* in_sizes, int n_in,
                              void* d_out, int out_size, void* d_ws, size_t ws_size,
                              hipStream_t stream)
{
    const float* x  = (const float*)d_in[0];
    const float* Wq = (const float*)d_in[1];
    const float* bq = (const float*)d_in[2];
    const float* Wk = (const float*)d_in[3];
    const float* bk = (const float*)d_in[4];
    const float* Wv = (const float*)d_in[5];
    const float* bv = (const float*)d_in[6];
    const float* Wo = (const float*)d_in[7];
    const float* bo = (const float*)d_in[8];

    char* p = (char*)d_ws;
    f16* xb  = (f16*)p;                 p += (size_t)NROW * EDIM * 2;   // 8 MB
    f16* Wqt = (f16*)p;                 p += (size_t)EDIM * EDIM * 2;   // 2 MB
    f16* Wkt = (f16*)p;                 p += (size_t)EDIM * EDIM * 2;
    f16* Wvt = (f16*)p;                 p += (size_t)EDIM * EDIM * 2;
    f16* Wot = (f16*)p;                 p += (size_t)EDIM * EDIM * 2;
    f16* Qhb = (f16*)p;                 p += (size_t)NROW * EDIM * 2;   // [b,h,s,d]
    f16* Khb = (f16*)p;                 p += (size_t)NROW * EDIM * 2;
    f16* Vtb = (f16*)p;                 p += (size_t)NROW * EDIM * 2;   // [b,h,d,s]
    f16* AOb = (f16*)p;                 p += (size_t)NROW * EDIM * 2;   // [b,s,e]

    // prep: weight transposes (z 0..3) + x cast (z 4) in one launch
    prep_kernel<<<dim3(32, 32, 5), 256, 0, stream>>>(x, xb, Wq, Wk, Wv, Wo,
                                                     Wqt, Wkt, Wvt, Wot);

    // fused Q/K/V projections: 128x128 tiles, 8 waves -> 768 blocks (r6)
    gemm_f16<128, 128, 4><<<dim3(NROW / 128, EDIM / 128, 3), 512, 0, stream>>>(
        xb, Wqt, Wkt, Wvt, bq, bk, bv, Qhb, Khb, Vtb, 1, 1, 2);

    // attention: T15 double-pipeline, triple-buffered K/V -> 512 blocks
    yat_attn<<<dim3(SEQ / 128, BATCH * NH), 512, 0, stream>>>(Qhb, Khb, Vtb, AOb);

    // output projection: 64x128 tiles -> 512 blocks (r6 config)
    gemm_f16<64, 128, 2><<<dim3(NROW / 64, EDIM / 128, 1), 256, 0, stream>>>(
        AOb, Wot, Wot, Wot, bo, bo, bo, d_out, d_out, d_out, 0, 0, 0);
}